// Round 5
// baseline (90.708 us; speedup 1.0000x reference)
//
#include <hip/hip_runtime.h>

#define D        4096
#define NERR     8192
#define D4       (D / 4)            // 1024 float4 per row
#define CHUNKS   128                // row chunks for partial column sums
#define RPC      (NERR / CHUNKS)    // 64 rows per chunk

typedef float f32x4 __attribute__((ext_vector_type(4)));

// ---------------- Kernel 1: partial column sums of |e|  +  bottom zero-fill
// grid = 1024 blocks x 256 threads.
//   blocks [0,512):  CHUNKS x 4 colblocks reduction; partials stored TRANSPOSED
//                    part_t[col*CHUNKS + chunk] (contiguous per column for K2).
//   blocks [512,1024): zero-fill the 64 MB bottom block with NT stores
//                    (overlaps the read stream; doesn't evict e from L3).
__global__ __launch_bounds__(256) void k_phase1(const f32x4* __restrict__ e4,
                                                float* __restrict__ part_t,
                                                f32x4* __restrict__ bot4) {
    const int t   = threadIdx.x;
    const int bid = blockIdx.x;
    if (bid < 512) {
        const int cb    = bid & 3;       // colblock of 256 f4-cols
        const int chunk = bid >> 2;      // 0..127
        const int col4  = cb * 256 + t;
        const f32x4* p  = e4 + (size_t)chunk * RPC * D4 + col4;

        f32x4 acc = (f32x4)(0.f, 0.f, 0.f, 0.f);
        #pragma unroll 8
        for (int r = 0; r < RPC; ++r) {
            f32x4 v = p[(size_t)r * D4];   // normal load: allocate e in L3
            acc.x += fabsf(v.x);
            acc.y += fabsf(v.y);
            acc.z += fabsf(v.z);
            acc.w += fabsf(v.w);
        }
        const size_t colbase = (size_t)col4 * 4;
        part_t[(colbase + 0) * CHUNKS + chunk] = acc.x;
        part_t[(colbase + 1) * CHUNKS + chunk] = acc.y;
        part_t[(colbase + 2) * CHUNKS + chunk] = acc.z;
        part_t[(colbase + 3) * CHUNKS + chunk] = acc.w;
    } else {
        const int fb = bid - 512;                  // 0..511
        const size_t base = (size_t)fb * 8192;     // f4 units; 64MB/512 blocks
        const f32x4 z = (f32x4)(0.f, 0.f, 0.f, 0.f);
        #pragma unroll
        for (int j = 0; j < 32; ++j)
            __builtin_nontemporal_store(z, &bot4[base + (size_t)j * 256 + t]);
    }
}

// ---------------- Kernel 2: per-column finalize + diagonal write --------
// grid = 256 blocks x 256 threads; one wave per 4 columns.
// part_t rows are contiguous (128 floats) -> coalesced wave loads + shuffle.
__global__ __launch_bounds__(256) void k_finalize(const float* __restrict__ part_t,
                                                  const float* __restrict__ center,
                                                  float* __restrict__ out_center,
                                                  float* __restrict__ col_scale,
                                                  float* __restrict__ out_bottom) {
    const int w    = threadIdx.x >> 6;
    const int lane = threadIdx.x & 63;
    const int colbase = blockIdx.x * 16 + w * 4;

    #pragma unroll
    for (int u = 0; u < 4; ++u) {
        const int col  = colbase + u;
        const float* p = part_t + (size_t)col * CHUNKS;
        float s = p[lane] + p[lane + 64];
        #pragma unroll
        for (int off = 32; off > 0; off >>= 1)
            s += __shfl_xor(s, off, 64);
        if (lane == 0) {
            const float apt = s;
            const float c   = center[col];
            const float ub  = c + apt;
            const float lb  = c - apt;
            const bool cross = (ub > 0.f) && (lb < 0.f);
            const bool act   = (lb >= 0.f);
            const float denom = cross ? (ub - lb) : 1.f;
            const float slope = cross ? (ub / denom) : 0.f;
            const float mu    = cross ? (-slope * lb * 0.5f) : 0.f;

            out_center[col] = act ? c : (slope * c + mu);
            col_scale[col]  = act ? 1.f : slope;
            out_bottom[(size_t)col * (D + 1)] = mu;   // diag over the zero-fill
        }
    }
}

// ---------------- Kernel 3: top = e * col_scale ------------------------
// grid-stride; stride (2048*256) is a multiple of D4 so each thread's
// column is loop-invariant. NT load (e is L3-resident; last use, don't
// re-allocate) + NT store (don't evict e while we stream).
__global__ __launch_bounds__(256) void k_scale_top(const f32x4* __restrict__ e4,
                                                   const f32x4* __restrict__ cs4,
                                                   f32x4* __restrict__ out4) {
    const int n4     = NERR * D4;                 // 8,388,608
    const int stride = gridDim.x * blockDim.x;    // 524,288 = 512*D4
    const int tid    = blockIdx.x * blockDim.x + threadIdx.x;
    const f32x4 s    = cs4[tid & (D4 - 1)];
    for (int i = tid; i < n4; i += stride) {
        f32x4 v = __builtin_nontemporal_load(&e4[i]);
        v *= s;
        __builtin_nontemporal_store(v, &out4[i]);
    }
}

extern "C" void kernel_launch(void* const* d_in, const int* in_sizes, int n_in,
                              void* d_out, int out_size, void* d_ws, size_t ws_size,
                              hipStream_t stream) {
    const float* center = (const float*)d_in[0];   // (4096,)
    const float* error  = (const float*)d_in[1];   // (8192, 4096)
    float* out = (float*)d_out;
    float* ws  = (float*)d_ws;

    // ws layout (floats): [part_t: D*CHUNKS = 2 MB][col_scale: D]
    float* part_t    = ws;
    float* col_scale = ws + (size_t)D * CHUNKS;

    float* out_center = out;                                   // (4096,)
    float* out_top    = out + D;                               // (8192, 4096)
    float* out_bottom = out + (size_t)D + (size_t)NERR * D;    // (4096, 4096)

    k_phase1<<<1024, 256, 0, stream>>>(
        (const f32x4*)error, part_t, (f32x4*)out_bottom);
    k_finalize<<<256, 256, 0, stream>>>(
        part_t, center, out_center, col_scale, out_bottom);
    k_scale_top<<<2048, 256, 0, stream>>>(
        (const f32x4*)error, (const f32x4*)col_scale, (f32x4*)out_top);
}

// Round 6
// 86.003 us; speedup vs baseline: 1.0547x; 1.0547x over previous
//
#include <hip/hip_runtime.h>

#define D        4096
#define NERR     8192
#define ROWCH    64                 // row chunks for partial column sums
#define RPC      (NERR / ROWCH)     // 128 rows per chunk
#define D4       (D / 4)            // 1024 float4 per row

typedef float f32x4 __attribute__((ext_vector_type(4)));  // NT-builtin-compatible

// ---------------- Kernel A: partial column sums of |e| ----------------
// grid = ROWCH * 4 = 256 blocks, 256 threads. Each block: 128 rows x 1024 f4-cols.
// Normal loads: allocate e into L3 (128 MB < 256 MB Infinity Cache).
__global__ void k_colsum_partial(const f32x4* __restrict__ e4,
                                 f32x4* __restrict__ part4) {
    const int t     = threadIdx.x;
    const int cb    = blockIdx.x & 3;     // 4 column blocks of 1024 f4-cols
    const int chunk = blockIdx.x >> 2;    // 64 row chunks
    const int col4  = cb * 256 + t;       // float4 column index [0,1024)
    const f32x4* p = e4 + (size_t)chunk * RPC * D4 + col4;

    f32x4 acc = (f32x4)(0.f, 0.f, 0.f, 0.f);
    #pragma unroll 8
    for (int r = 0; r < RPC; ++r) {
        f32x4 v = p[(size_t)r * D4];
        acc.x += fabsf(v.x);
        acc.y += fabsf(v.y);
        acc.z += fabsf(v.z);
        acc.w += fabsf(v.w);
    }
    part4[chunk * D4 + col4] = acc;
}

// ---------------- Kernel B: reduce partials + per-column transform -----
// grid = D/256 = 16 blocks, 256 threads; one thread per column. 1 MB read.
__global__ void k_finalize_cols(const float* __restrict__ part,
                                const float* __restrict__ center,
                                float* __restrict__ out_center,
                                float* __restrict__ col_scale,
                                float* __restrict__ mu_arr) {
    const int col = blockIdx.x * 256 + threadIdx.x;
    float apt = 0.f;
    #pragma unroll 8
    for (int k = 0; k < ROWCH; ++k) apt += part[k * D + col];

    const float c  = center[col];
    const float ub = c + apt;
    const float lb = c - apt;
    const bool cross = (ub > 0.f) && (lb < 0.f);
    const bool act   = (lb >= 0.f);

    const float denom = cross ? (ub - lb) : 1.f;
    const float slope = cross ? (ub / denom) : 0.f;
    const float mu    = cross ? (-slope * lb * 0.5f) : 0.f;

    out_center[col] = act ? c : (slope * c + mu);
    col_scale[col]  = act ? 1.f : slope;
    mu_arr[col]     = mu;
}

// ---------------- Kernel C: top = e * col_scale ------------------------
// grid-stride; stride (2048*256) is a multiple of D4 so each thread's
// column is loop-invariant -> hoist the scale load. NORMAL load for e
// (hit the L3 copy kernel A allocated); NT store (streaming output,
// don't evict e).
__global__ void k_scale_top(const f32x4* __restrict__ e4,
                            const f32x4* __restrict__ cs4,
                            f32x4* __restrict__ out4) {
    const int n4     = NERR * D4;                 // 8,388,608
    const int stride = gridDim.x * blockDim.x;    // 524,288 = 512*D4
    const int tid    = blockIdx.x * blockDim.x + threadIdx.x;
    const f32x4 s    = cs4[tid & (D4 - 1)];
    for (int i = tid; i < n4; i += stride) {
        f32x4 v = e4[i];                          // normal load: L3 hit path
        v *= s;
        __builtin_nontemporal_store(v, &out4[i]);
    }
}

// ---------------- Kernel D: bottom = diag(mu) --------------------------
// grid-stride; zeros except one diag element per row. NT stores.
__global__ void k_write_bottom(const float* __restrict__ mu_arr,
                               f32x4* __restrict__ out4) {
    const int n4     = D * D4;                    // 4,194,304
    const int stride = gridDim.x * blockDim.x;
    const int tid    = blockIdx.x * blockDim.x + threadIdx.x;
    const int j4     = tid & (D4 - 1);            // loop-invariant f4-col
    for (int i = tid; i < n4; i += stride) {
        const int row = i >> 10;                  // / D4
        f32x4 v = (f32x4)(0.f, 0.f, 0.f, 0.f);
        if (j4 == (row >> 2)) {
            v[row & 3] = mu_arr[row];
        }
        __builtin_nontemporal_store(v, &out4[i]);
    }
}

extern "C" void kernel_launch(void* const* d_in, const int* in_sizes, int n_in,
                              void* d_out, int out_size, void* d_ws, size_t ws_size,
                              hipStream_t stream) {
    const float* center = (const float*)d_in[0];   // (4096,)
    const float* error  = (const float*)d_in[1];   // (8192, 4096)
    float* out = (float*)d_out;
    float* ws  = (float*)d_ws;

    // ws layout (floats): [partials: ROWCH*D = 1 MB][col_scale: D][mu: D]
    float* part      = ws;
    float* col_scale = ws + (size_t)ROWCH * D;
    float* mu_arr    = col_scale + D;

    float* out_center = out;                                   // (4096,)
    float* out_top    = out + D;                               // (8192, 4096)
    float* out_bottom = out + (size_t)D + (size_t)NERR * D;    // (4096, 4096)

    k_colsum_partial<<<ROWCH * 4, 256, 0, stream>>>(
        (const f32x4*)error, (f32x4*)part);
    k_finalize_cols<<<D / 256, 256, 0, stream>>>(
        part, center, out_center, col_scale, mu_arr);
    k_scale_top<<<2048, 256, 0, stream>>>(
        (const f32x4*)error, (const f32x4*)col_scale, (f32x4*)out_top);
    k_write_bottom<<<2048, 256, 0, stream>>>(
        mu_arr, (f32x4*)out_bottom);
}

// Round 7
// 82.722 us; speedup vs baseline: 1.0965x; 1.0397x over previous
//
#include <hip/hip_runtime.h>

#define D       4096
#define NERR    8192
#define DF4     (D / 4)            // 1024 f4-cols per row
#define NSTRIP  128                // strip blocks; strip = 8 f4-cols = 32 cols
#define SF4     (DF4 / NSTRIP)     // 8 f4-cols per strip (128 B per row segment)
#define TPB     1024
#define RPP     (TPB / SF4)        // 128 rows covered per pass
#define NPASS   (NERR / RPP)       // 64 passes

typedef float f32x4 __attribute__((ext_vector_type(4)));

// One kernel. Blocks [0,128): fused reduce+finalize+scale for one 32-col strip.
// Blocks [128,256): zero-fill the bottom block (minus diagonal f4s, which the
// strip blocks write with mu). Disjoint writes -> no ordering assumptions.
__global__ __launch_bounds__(TPB) void k_fused(const f32x4* __restrict__ e4,
                                               const f32x4* __restrict__ c4,
                                               f32x4* __restrict__ out_center4,
                                               f32x4* __restrict__ top4,
                                               f32x4* __restrict__ bot4) {
    __shared__ f32x4 red[TPB];     // 16 KB reduction staging
    __shared__ f32x4 scl[SF4];     // per-f4-col scale broadcast

    const int t   = threadIdx.x;
    const int bid = blockIdx.x;

    if (bid < NSTRIP) {
        const int s   = bid;
        const int cf  = t & (SF4 - 1);      // f4-col within strip, 0..7
        const int r0  = t >> 3;             // row within pass, 0..127
        const int off = s * SF4 + cf;       // global f4-col

        // ---- phase 1: |e| column sums over the strip (HBM read, allocate)
        f32x4 acc = (f32x4)(0.f, 0.f, 0.f, 0.f);
        #pragma unroll 8
        for (int k = 0; k < NPASS; ++k) {
            const int r = r0 + k * RPP;
            f32x4 v = e4[(size_t)r * DF4 + off];
            acc.x += fabsf(v.x);
            acc.y += fabsf(v.y);
            acc.z += fabsf(v.z);
            acc.w += fabsf(v.w);
        }
        red[t] = acc;
        __syncthreads();
        #pragma unroll
        for (int step = 64; step >= 1; step >>= 1) {
            if (r0 < step) red[t] += red[t + step * SF4];
            __syncthreads();
        }

        // ---- finalize: 8 threads each handle one f4-col (4 columns)
        if (t < SF4) {
            const int g  = s * SF4 + t;     // global f4-col
            const f32x4 apt = red[t];
            const f32x4 cen = c4[g];
            f32x4 oc, cs;
            #pragma unroll
            for (int j = 0; j < 4; ++j) {
                const float c  = cen[j];
                const float ub = c + apt[j];
                const float lb = c - apt[j];
                const bool cross = (ub > 0.f) && (lb < 0.f);
                const bool act   = (lb >= 0.f);
                const float denom = cross ? (ub - lb) : 1.f;
                const float slope = cross ? (ub / denom) : 0.f;
                const float mu    = cross ? (-slope * lb * 0.5f) : 0.f;
                oc[j] = act ? c : (slope * c + mu);
                cs[j] = act ? 1.f : slope;
                // diagonal f4 of row (4g+j): zeros except slot j = mu
                f32x4 dv = (f32x4)(0.f, 0.f, 0.f, 0.f);
                dv[j] = mu;
                __builtin_nontemporal_store(dv, &bot4[(size_t)(4 * g + j) * DF4 + g]);
            }
            out_center4[g] = oc;
            scl[t] = cs;
        }
        __syncthreads();

        // ---- phase 2: re-read strip (1 MB reuse distance -> L2/L3) and
        //      write scaled top with NT stores (don't evict other strips)
        const f32x4 cs = scl[cf];
        #pragma unroll 8
        for (int k = 0; k < NPASS; ++k) {
            const int r = r0 + k * RPP;
            f32x4 v = e4[(size_t)r * DF4 + off];
            v *= cs;
            __builtin_nontemporal_store(v, &top4[(size_t)r * DF4 + off]);
        }
    } else {
        // ---- bottom zero-fill: 32 rows per block, skip the diagonal f4
        const int fb   = bid - NSTRIP;      // 0..127
        const int row0 = fb * 32;
        const f32x4 z = (f32x4)(0.f, 0.f, 0.f, 0.f);
        #pragma unroll 4
        for (int j = 0; j < 32; ++j) {
            const int row = row0 + j;
            const int dg  = row >> 2;       // diagonal f4-col of this row
            if (t != dg)
                __builtin_nontemporal_store(z, &bot4[(size_t)row * DF4 + t]);
        }
    }
}

extern "C" void kernel_launch(void* const* d_in, const int* in_sizes, int n_in,
                              void* d_out, int out_size, void* d_ws, size_t ws_size,
                              hipStream_t stream) {
    const float* center = (const float*)d_in[0];   // (4096,)
    const float* error  = (const float*)d_in[1];   // (8192, 4096)
    float* out = (float*)d_out;

    float* out_center = out;                                   // (4096,)
    float* out_top    = out + D;                               // (8192, 4096)
    float* out_bottom = out + (size_t)D + (size_t)NERR * D;    // (4096, 4096)

    k_fused<<<2 * NSTRIP, TPB, 0, stream>>>(
        (const f32x4*)error, (const f32x4*)center,
        (f32x4*)out_center, (f32x4*)out_top, (f32x4*)out_bottom);
}